// Round 1
// baseline (216.585 us; speedup 1.0000x reference)
//
#include <hip/hip_runtime.h>
#include <math.h>

// Topology (hard-coded from the reference's _build_grid):
//   n = GRID_N nodes/side, m = n-1 plaquettes/side, nH = n*m horizontal edges.
//   Plaquette (pi,pj) vars: a=(pi,pj) b=(pi,pj+1) c=(pi+1,pj) d=(pi+1,pj+1)
//   slot0 = top horiz edge    e = pi*m+pj       over (a,b); other parent (pi-1,pj) slot1
//   slot1 = bottom horiz edge e = (pi+1)*m+pj   over (c,d); other parent (pi+1,pj) slot0
//   slot2 = left vert edge    e = nH+pi*n+pj    over (a,c); other parent (pi,pj-1) slot3
//   slot3 = right vert edge   e = nH+pi*n+pj+1  over (b,d); other parent (pi,pj+1) slot2
// Own-parent message cancels in n_all = tot - logM_own, so
//   n_all[p,s] = phi_edge[e_s] + logM[other_parent, other_slot]  (0 if boundary).

static __device__ __forceinline__ float4 ld4(const float* p){
  return *(const float4*)p;
}
static __device__ __forceinline__ void add4(float* dst, float4 pe, float4 o){
  dst[0]=pe.x+o.x; dst[1]=pe.y+o.y; dst[2]=pe.z+o.z; dst[3]=pe.w+o.w;
}

__global__ __launch_bounds__(256)
void init_kernel(float4* __restrict__ M, int n4, float* __restrict__ Facc){
  int i = blockIdx.x*256 + threadIdx.x;
  const float v = -1.3862943611198906f; // -log(4)
  if (i < n4) M[i] = make_float4(v,v,v,v);
  if (i == 0){ Facc[0]=0.f; Facc[1]=0.f; }
}

static __device__ __forceinline__
void load_na(const float* __restrict__ phiE, const float* __restrict__ M,
             int pi, int pj, int m, int n, float na[4][4])
{
  const int p  = pi*m + pj;
  const int nH = n*m;
  const float4 z = make_float4(0.f,0.f,0.f,0.f);
  { // slot 0
    float4 pe = ld4(phiE + 4*(size_t)(pi*m + pj));
    float4 o  = (pi > 0)   ? ld4(M + 16*(size_t)(p - m) + 4)  : z;
    add4(na[0], pe, o);
  }
  { // slot 1
    float4 pe = ld4(phiE + 4*(size_t)((pi+1)*m + pj));
    float4 o  = (pi < m-1) ? ld4(M + 16*(size_t)(p + m) + 0)  : z;
    add4(na[1], pe, o);
  }
  { // slot 2
    float4 pe = ld4(phiE + 4*(size_t)(nH + pi*n + pj));
    float4 o  = (pj > 0)   ? ld4(M + 16*(size_t)(p - 1) + 12) : z;
    add4(na[2], pe, o);
  }
  { // slot 3
    float4 pe = ld4(phiE + 4*(size_t)(nH + pi*n + pj + 1));
    float4 o  = (pj < m-1) ? ld4(M + 16*(size_t)(p + 1) + 8)  : z;
    add4(na[3], pe, o);
  }
}

__global__ __launch_bounds__(256)
void step_kernel(const float* __restrict__ phiP, const float* __restrict__ phiE,
                 const float* __restrict__ Mold, float* __restrict__ Mnew,
                 int m, int n)
{
  int pj = blockIdx.x*64 + threadIdx.x;
  int pi = blockIdx.y*4  + threadIdx.y;
  if (pi >= m || pj >= m) return;
  const int p = pi*m + pj;

  float na[4][4];
  load_na(phiE, Mold, pi, pj, m, n, na);

  float ph[16];
  {
    const float* pp = phiP + 16*(size_t)p;
    ((float4*)ph)[0]=ld4(pp);    ((float4*)ph)[1]=ld4(pp+4);
    ((float4*)ph)[2]=ld4(pp+8);  ((float4*)ph)[3]=ld4(pp+12);
  }

  // S[a,b,c,d] = phi + b0(a,b) + b1(c,d) + b2(a,c) + b3(b,d)
  float S[16]; float Smax = -3.0e38f;
  #pragma unroll
  for (int idx=0; idx<16; ++idx){
    const int a=(idx>>3)&1, b=(idx>>2)&1, c=(idx>>1)&1, d=idx&1;
    float s = ph[idx] + na[0][(a<<1)|b] + na[1][(c<<1)|d]
                      + na[2][(a<<1)|c] + na[3][(b<<1)|d];
    S[idx]=s; Smax=fmaxf(Smax,s);
  }
  // One shared set of 16 exps feeds all four marginalizations:
  // m_s[k] = Smax + log(group_sum) - na[s][k]  (broadcast term constant in group)
  float g[4][4];
  #pragma unroll
  for (int s=0;s<4;s++){ g[s][0]=0.f; g[s][1]=0.f; g[s][2]=0.f; g[s][3]=0.f; }
  #pragma unroll
  for (int idx=0; idx<16; ++idx){
    const int a=(idx>>3)&1, b=(idx>>2)&1, c=(idx>>1)&1, d=idx&1;
    float e = __expf(S[idx]-Smax);
    g[0][(a<<1)|b]+=e; g[1][(c<<1)|d]+=e; g[2][(a<<1)|c]+=e; g[3][(b<<1)|d]+=e;
  }
  float out[16];
  #pragma unroll
  for (int s=0;s<4;s++){
    float mm[4]; float r=-3.0e38f;
    #pragma unroll
    for (int k=0;k<4;k++){
      mm[k] = Smax + __logf(fmaxf(g[s][k],1e-37f)) - na[s][k];
      r = fmaxf(r, mm[k]);
    }
    float zz=0.f;
    #pragma unroll
    for (int k=0;k<4;k++) zz += __expf(mm[k]-r);
    float lz = r + __logf(zz);
    #pragma unroll
    for (int k=0;k<4;k++) out[(s<<2)|k] = mm[k]-lz;
  }
  float* dst = Mnew + 16*(size_t)p;
  ((float4*)dst)[0]=((float4*)out)[0];
  ((float4*)dst)[1]=((float4*)out)[1];
  ((float4*)dst)[2]=((float4*)out)[2];
  ((float4*)dst)[3]=((float4*)out)[3];
}

// Edge beliefs: b_e = softmax(tot); writes binary marginals (unaligned by 1
// float in d_out -> scalar stores); interior edges (2 parents) contribute
// c_e=-1 times their KL term to F.
__global__ __launch_bounds__(256)
void edge_final_kernel(const float* __restrict__ phiE, const float* __restrict__ M,
                       float* __restrict__ outBin, float* __restrict__ Facc,
                       int m, int n, int E)
{
  int e = blockIdx.x*256 + threadIdx.x;
  float contrib = 0.f;
  if (e < E){
    const int nH = n*m;
    float4 pe = ld4(phiE + 4*(size_t)e);
    float t0=pe.x, t1=pe.y, t2=pe.z, t3=pe.w;
    int npar = 0;
    if (e < nH){
      int hi = e / m, hj = e - hi*m;
      if (hi < m){ float4 o = ld4(M + 16*(size_t)(hi*m+hj) + 0);
                   t0+=o.x; t1+=o.y; t2+=o.z; t3+=o.w; npar++; }
      if (hi > 0){ float4 o = ld4(M + 16*(size_t)((hi-1)*m+hj) + 4);
                   t0+=o.x; t1+=o.y; t2+=o.z; t3+=o.w; npar++; }
    } else {
      int v = e - nH; int vi = v / n, vj = v - vi*n;
      if (vj < m){ float4 o = ld4(M + 16*(size_t)(vi*m+vj) + 8);
                   t0+=o.x; t1+=o.y; t2+=o.z; t3+=o.w; npar++; }
      if (vj > 0){ float4 o = ld4(M + 16*(size_t)(vi*m+vj-1) + 12);
                   t0+=o.x; t1+=o.y; t2+=o.z; t3+=o.w; npar++; }
    }
    float r = fmaxf(fmaxf(t0,t1), fmaxf(t2,t3));
    float e0=__expf(t0-r), e1=__expf(t1-r), e2=__expf(t2-r), e3=__expf(t3-r);
    float Z = e0+e1+e2+e3;
    float lse = r + __logf(Z);
    float invZ = 1.f/Z;
    float b0=e0*invZ, b1=e1*invZ, b2=e2*invZ, b3=e3*invZ;
    float* ob = outBin + 4*(size_t)e;
    ob[0]=b0; ob[1]=b1; ob[2]=b2; ob[3]=b3;
    if (npar == 2){
      contrib = -( b0*(t0-lse-pe.x) + b1*(t1-lse-pe.y)
                 + b2*(t2-lse-pe.z) + b3*(t3-lse-pe.w) );
    }
  }
  __shared__ float red[256];
  int t = threadIdx.x;
  red[t] = contrib; __syncthreads();
  #pragma unroll
  for (int s=128; s>0; s>>=1){
    if (t < s) red[t] += red[t+s];
    __syncthreads();
  }
  if (t == 0) atomicAdd(&Facc[1], red[0]);
}

__global__ __launch_bounds__(256)
void plaq_final_kernel(const float* __restrict__ phiP, const float* __restrict__ phiE,
                       const float* __restrict__ M, float* __restrict__ Facc,
                       int m, int n, int P)
{
  int p = blockIdx.x*256 + threadIdx.x;
  float contrib = 0.f;
  if (p < P){
    int pi = p / m, pj = p - pi*m;
    float na[4][4];
    load_na(phiE, M, pi, pj, m, n, na);
    float ph[16];
    {
      const float* pp = phiP + 16*(size_t)p;
      ((float4*)ph)[0]=ld4(pp);    ((float4*)ph)[1]=ld4(pp+4);
      ((float4*)ph)[2]=ld4(pp+8);  ((float4*)ph)[3]=ld4(pp+12);
    }
    float S[16]; float Smax=-3.0e38f;
    #pragma unroll
    for (int idx=0; idx<16; ++idx){
      const int a=(idx>>3)&1, b=(idx>>2)&1, c=(idx>>1)&1, d=idx&1;
      float s = ph[idx] + na[0][(a<<1)|b] + na[1][(c<<1)|d]
                        + na[2][(a<<1)|c] + na[3][(b<<1)|d];
      S[idx]=s; Smax=fmaxf(Smax,s);
    }
    float Es[16]; float Z=0.f;
    #pragma unroll
    for (int idx=0; idx<16; ++idx){ Es[idx]=__expf(S[idx]-Smax); Z+=Es[idx]; }
    float lse  = Smax + __logf(Z);
    float invZ = 1.f/Z;
    #pragma unroll
    for (int idx=0; idx<16; ++idx)
      contrib += (Es[idx]*invZ) * (S[idx]-lse-ph[idx]);
  }
  __shared__ float red[256];
  int t = threadIdx.x;
  red[t] = contrib; __syncthreads();
  #pragma unroll
  for (int s=128; s>0; s>>=1){
    if (t < s) red[t] += red[t+s];
    __syncthreads();
  }
  if (t == 0) atomicAdd(&Facc[0], red[0]);
}

// Unary marginals: average incident-edge marginals (deg in {2,3,4}), read
// straight from the binary-marginal region of d_out. Thread (0,0) writes -F.
__global__ __launch_bounds__(256)
void unary_kernel(const float* __restrict__ bin, float* __restrict__ out,
                  const float* __restrict__ Facc, int m, int n)
{
  int j = blockIdx.x*64 + threadIdx.x;
  int i = blockIdx.y*4  + threadIdx.y;
  if (i >= n || j >= n) return;
  const int nH = n*m;
  float s0=0.f, s1=0.f, deg=0.f;
  if (j < m){ const float* b = bin + 4*(size_t)(i*m+j);        s0 += b[0]+b[1]; s1 += b[2]+b[3]; deg+=1.f; } // right horiz, endpoint 0
  if (j > 0){ const float* b = bin + 4*(size_t)(i*m+j-1);      s0 += b[0]+b[2]; s1 += b[1]+b[3]; deg+=1.f; } // left horiz,  endpoint 1
  if (i < m){ const float* b = bin + 4*(size_t)(nH+i*n+j);     s0 += b[0]+b[1]; s1 += b[2]+b[3]; deg+=1.f; } // down vert,   endpoint 0
  if (i > 0){ const float* b = bin + 4*(size_t)(nH+(i-1)*n+j); s0 += b[0]+b[2]; s1 += b[1]+b[3]; deg+=1.f; } // up vert,     endpoint 1
  float inv = 1.f/deg;
  size_t v = (size_t)i*n + j;
  out[1+2*v]   = s0*inv;
  out[1+2*v+1] = s1*inv;
  if (i==0 && j==0) out[0] = -(Facc[0]+Facc[1]);
}

extern "C" void kernel_launch(void* const* d_in, const int* in_sizes, int n_in,
                              void* d_out, int out_size, void* d_ws, size_t ws_size,
                              hipStream_t stream)
{
  const float* phiP = (const float*)d_in[0];
  const float* phiE = (const float*)d_in[1];
  // d_in[2..6] (index arrays) unused: grid topology is deterministic and
  // hard-coded. d_in[7] (n_iters=5) is a device scalar -> hard-coded (cannot
  // be read host-side under graph capture; reference fixes N_ITERS=5).
  const int P  = in_sizes[0] / 16;
  const int m  = (int)(sqrt((double)P) + 0.5);   // 511
  const int n  = m + 1;                          // 512
  const int E  = in_sizes[1] / 4;
  const int Nv = n * n;
  float* out = (float*)d_out;

  float* MA   = (float*)d_ws;                    // P*16 floats
  float* MB   = MA + (size_t)P*16;               // P*16 floats
  float* Facc = MB + (size_t)P*16;               // [0]=plaq F, [1]=edge F

  const int n4 = P*4;
  init_kernel<<<dim3((n4+255)/256), dim3(256), 0, stream>>>((float4*)MA, n4, Facc);

  dim3 blk(64,4), grd((m+63)/64, (m+3)/4);
  float* cur = MA; float* nxt = MB;
  for (int it=0; it<5; ++it){
    step_kernel<<<grd, blk, 0, stream>>>(phiP, phiE, cur, nxt, m, n);
    float* t = cur; cur = nxt; nxt = t;
  }

  float* outBin = out + 1 + 2*(size_t)Nv;
  edge_final_kernel<<<dim3((E+255)/256), dim3(256), 0, stream>>>(phiE, cur, outBin, Facc, m, n, E);
  plaq_final_kernel<<<dim3((P+255)/256), dim3(256), 0, stream>>>(phiP, phiE, cur, Facc, m, n, P);
  unary_kernel<<<dim3((n+63)/64, (n+3)/4), dim3(64,4), 0, stream>>>(outBin, out, Facc, m, n);
}